// Round 7
// baseline (2467.139 us; speedup 1.0000x reference)
//
#include <hip/hip_runtime.h>

// B=256, T=2048, F=64, U=10 LSTM (Keras gates i,f,g,o; softsign cell act).
// One block (192 thr) per batch element. Wave0 = sequential scan (lane
// L=u*4+gate owns matrix column col=gate*10+u; gate gather via DPP quad
// broadcasts). Waves 1-2 = producers, TRANSPOSED mapping: lane = timestep,
// 20 gate-columns per wave as 5 float4 accumulators in NATURAL column order;
// x rows loaded per-lane from global (register buffer, reloaded one chunk
// early); W read from LDS as all-lane-uniform b128 broadcasts (~zero LDS
// pipe occupancy). z rows padded to 44 floats.
// R6 BUG FIXED: producer writes z in natural column order, so the scan lane
// must read zb at offset col (=gate*10+u), NOT at L (=u*4+gate).
#define B_ 256
#define T_ 2048
#define F_ 64
#define U_ 10
#define G_ 40
#define CH 64          // timesteps per chunk
#define NCH (T_ / CH)  // 32
#define ZP 44          // padded z row stride (floats), 16B-aligned

__device__ __forceinline__ float rcp_f(float x) { return __builtin_amdgcn_rcpf(x); }
__device__ __forceinline__ float rdlane_f(float v, int l) {
  return __int_as_float(__builtin_amdgcn_readlane(__float_as_int(v), l));
}
template <int CTRL>
__device__ __forceinline__ float qbcast(float v) {  // quad_perm broadcast
  return __int_as_float(
      __builtin_amdgcn_update_dpp(0, __float_as_int(v), CTRL, 0xF, 0xF, true));
}

__global__ __launch_bounds__(192, 1) void lstm_fused(
    const float* __restrict__ x, const float* __restrict__ W,
    const float* __restrict__ R, const float* __restrict__ bias,
    const float* __restrict__ dw, const float* __restrict__ db,
    float* __restrict__ out) {
  __shared__ alignas(16) float Wl[F_ * G_];     // 10 KB W copy (uniform reads)
  __shared__ alignas(16) float zb[2][CH * ZP];  // 2 x 11 KB z chunks
  const int b = blockIdx.x;
  const int tid = threadIdx.x;
  const int wave = tid >> 6;
  const int lane = tid & 63;
  const float* xbase = x + (size_t)b * T_ * F_;

  if (wave == 0) {
    // ---------------- scan wave ----------------
    __builtin_amdgcn_s_setprio(3);
    const int L = (lane < G_) ? lane : (G_ - 1);
    const int u = L >> 2, gate = L & 3;
    const int col = gate * U_ + u;   // natural column index this lane owns
    float Rc[U_];
    #pragma unroll
    for (int j = 0; j < U_; ++j) Rc[j] = R[j * G_ + col];
    const float dwu = dw[u];
    const float db0 = db[0];
    float h = 0.f, c = 0.f;
    __syncthreads();  // B-W: W staged
    __syncthreads();  // B-z0: z(0) produced
    for (int cc = 0; cc < NCH; ++cc) {
      const float* zrow = zb[cc & 1] + col;  // FIX: read natural-order z
      float zpf[4];
      #pragma unroll
      for (int k = 0; k < 4; ++k) zpf[k] = zrow[k * ZP];
      for (int t0 = 0; t0 < CH; t0 += 4) {
        #pragma unroll
        for (int k = 0; k < 4; ++k) {
          float z0 = zpf[k];
          int tn = t0 + 4 + k;               // 4-ahead LDS prefetch
          if (tn > CH - 1) tn = CH - 1;      // clamp (stale value unused)
          zpf[k] = zrow[tn * ZP];
          float z1 = 0.f;
          #pragma unroll
          for (int j = 0; j < U_; j += 2) {  // even/odd: 5-deep fma chains
            float ha = rdlane_f(h, 4 * j);
            float hb = rdlane_f(h, 4 * (j + 1));
            z0 = fmaf(ha, Rc[j], z0);
            z1 = fmaf(hb, Rc[j + 1], z1);
          }
          float zz = z0 + z1;
          float sg = rcp_f(1.f + __expf(-zz));               // sigmoid
          float ss = zz * rcp_f(1.f + __builtin_fabsf(zz));  // softsign
          float a = (gate == 2) ? ss : sg;                   // cndmask
          float ai = qbcast<0x00>(a);
          float af = qbcast<0x55>(a);
          float ag = qbcast<0xAA>(a);
          float ao = qbcast<0xFF>(a);
          c = fmaf(af, c, ai * ag);
          float oc = ao * c;
          float den = 1.f + __builtin_fabsf(c);
          h = oc * rcp_f(den);                               // o*softsign(c)
        }
      }
      __syncthreads();  // B(cc)
    }
    // epilogue: logit = sum_u h[u]*dw[u] + db; out = sigmoid(logit)
    float p = h * dwu;
    float logit = db0;
    #pragma unroll
    for (int j = 0; j < U_; ++j) logit += rdlane_f(p, 4 * j);
    if (lane == 0) out[b] = rcp_f(1.f + __expf(-logit));
  } else {
    // ---------------- producer waves (1..2): lane = timestep ----------------
    const int pw = wave - 1;        // 0..1
    const int base = pw * 20;       // this wave's 20 natural columns
    // stage W into LDS (both producer waves, coalesced)
    for (int i = tid - 64; i < F_ * G_; i += 128) Wl[i] = W[i];
    float4 bb[5];
    #pragma unroll
    for (int q = 0; q < 5; ++q) bb[q] = ((const float4*)(bias + base))[q];

    float4 A[16];  // my timestep's x row (64 floats)
    auto loadA = [&](int cc) {
      const float4* xr = (const float4*)(xbase + (size_t)cc * CH * F_) + lane * 16;
      #pragma unroll
      for (int j = 0; j < 16; ++j) A[j] = xr[j];
    };
    auto produce = [&](int tc, int loadnext) {
      float4 a0 = bb[0], a1 = bb[1], a2 = bb[2], a3 = bb[3], a4 = bb[4];
      #pragma unroll
      for (int k = 0; k < F_; ++k) {
        const float4* wk = (const float4*)(Wl + k * G_ + base);  // uniform addr
        float4 w0 = wk[0], w1 = wk[1], w2 = wk[2], w3 = wk[3], w4 = wk[4];
        float4 av = A[k >> 2];
        float xk = ((k & 3) == 0) ? av.x : ((k & 3) == 1) ? av.y
                 : ((k & 3) == 2) ? av.z : av.w;                 // compile-time
        a0.x = fmaf(xk, w0.x, a0.x); a0.y = fmaf(xk, w0.y, a0.y);
        a0.z = fmaf(xk, w0.z, a0.z); a0.w = fmaf(xk, w0.w, a0.w);
        a1.x = fmaf(xk, w1.x, a1.x); a1.y = fmaf(xk, w1.y, a1.y);
        a1.z = fmaf(xk, w1.z, a1.z); a1.w = fmaf(xk, w1.w, a1.w);
        a2.x = fmaf(xk, w2.x, a2.x); a2.y = fmaf(xk, w2.y, a2.y);
        a2.z = fmaf(xk, w2.z, a2.z); a2.w = fmaf(xk, w2.w, a2.w);
        a3.x = fmaf(xk, w3.x, a3.x); a3.y = fmaf(xk, w3.y, a3.y);
        a3.z = fmaf(xk, w3.z, a3.z); a3.w = fmaf(xk, w3.w, a3.w);
        a4.x = fmaf(xk, w4.x, a4.x); a4.y = fmaf(xk, w4.y, a4.y);
        a4.z = fmaf(xk, w4.z, a4.z); a4.w = fmaf(xk, w4.w, a4.w);
      }
      if (loadnext) loadA(tc + 1);  // overlap next chunk's x latency
      float4* zr = (float4*)(zb[tc & 1] + lane * ZP + base);
      zr[0] = a0; zr[1] = a1; zr[2] = a2; zr[3] = a3; zr[4] = a4;
    };

    loadA(0);
    __syncthreads();  // B-W: W staged
    produce(0, 1);
    __syncthreads();  // B-z0
    for (int cc = 0; cc < NCH; ++cc) {
      if (cc + 1 < NCH) produce(cc + 1, cc + 2 < NCH);
      __syncthreads();  // B(cc)
    }
  }
}

extern "C" void kernel_launch(void* const* d_in, const int* in_sizes, int n_in,
                              void* d_out, int out_size, void* d_ws, size_t ws_size,
                              hipStream_t stream) {
  const float* x    = (const float*)d_in[0];  // [256,2048,64]
  const float* W    = (const float*)d_in[1];  // [64,40]
  const float* R    = (const float*)d_in[2];  // [10,40]
  const float* bias = (const float*)d_in[3];  // [40]
  const float* dw   = (const float*)d_in[4];  // [10,1]
  const float* db   = (const float*)d_in[5];  // [1]
  float* out = (float*)d_out;                 // [256]
  (void)d_ws; (void)ws_size; (void)in_sizes; (void)n_in; (void)out_size;
  lstm_fused<<<B_, 192, 0, stream>>>(x, W, R, bias, dw, db, out);
}